// Round 9
// baseline (4094.522 us; speedup 1.0000x reference)
//
#include <hip/hip_runtime.h>
#include <hip/hip_bf16.h>
#include <hip/hip_fp16.h>

#define SETS 2048
#define SS   36
#define CDIM 192
#define HEADS 8
#define DH   24
#define FDIM 384
#define NVOX (SETS*SS)   /* 73728 */
#define NBLOCKS 4

typedef __hip_bfloat16 bf16;
typedef _Float16 f16;
typedef __attribute__((ext_vector_type(2))) _Float16 h2v;
typedef __attribute__((ext_vector_type(4))) short s4v;
typedef __attribute__((ext_vector_type(8))) short s8v;
typedef __attribute__((ext_vector_type(4))) float f4v;

__device__ __forceinline__ short f2bf(float x) {
  bf16 h = __float2bfloat16(x);
  return *reinterpret_cast<short*>(&h);
}
__device__ __forceinline__ unsigned pack2(float a, float b) {
  return ((unsigned)(unsigned short)f2bf(a)) | (((unsigned)(unsigned short)f2bf(b)) << 16);
}

// packed f16 dot2 with f32 accumulate: acc + a.lo*b.lo + a.hi*b.hi
__device__ __forceinline__ float dot2(unsigned a, unsigned b, float acc) {
#if __has_builtin(__builtin_amdgcn_fdot2)
  return __builtin_amdgcn_fdot2(__builtin_bit_cast(h2v, a), __builtin_bit_cast(h2v, b), acc, false);
#else
  h2v ha = __builtin_bit_cast(h2v, a), hb = __builtin_bit_cast(h2v, b);
  return acc + (float)ha[0] * (float)hb[0] + (float)ha[1] * (float)hb[1];
#endif
}
// pack two f32 -> packed f16 pair (round-to-zero)
__device__ __forceinline__ unsigned pkh(float a, float b) {
#if __has_builtin(__builtin_amdgcn_cvt_pkrtz)
  return __builtin_bit_cast(unsigned, __builtin_amdgcn_cvt_pkrtz(a, b));
#else
  h2v h; h[0] = (f16)a; h[1] = (f16)b;
  return __builtin_bit_cast(unsigned, h);
#endif
}
// byte-perm: lo-half picks from a, hi-half from b (with our sel constants)
__device__ __forceinline__ unsigned permw(unsigned a, unsigned b, unsigned sel) {
#if __has_builtin(__builtin_amdgcn_perm)
  return __builtin_amdgcn_perm(b, a, sel);
#else
  if (sel == 0x05040100u) return (a & 0xffffu) | (b << 16);
  return (a >> 16) | (b & 0xffff0000u);
#endif
}

// LN over a row held as 12 regs x 16 lanes (quad-local): reduce = 12 adds +
// 4 shfl_xor (xor bits 0-3 keep the quad intact). g/b come from LDS (broadcast
// across quads, conflict-free).
__device__ __forceinline__ void lnq(float v[12], const float* g, const float* b, int l16) {
  float s = 0.f;
  #pragma unroll
  for (int j = 0; j < 12; j++) s += v[j];
  #pragma unroll
  for (int off = 8; off > 0; off >>= 1) s += __shfl_xor(s, off);
  float m = s * (1.0f / 192.0f);
  float q = 0.f;
  #pragma unroll
  for (int j = 0; j < 12; j++) { float d = v[j] - m; q += d * d; }
  #pragma unroll
  for (int off = 8; off > 0; off >>= 1) q += __shfl_xor(q, off);
  float rs = rsqrtf(q * (1.0f / 192.0f) + 1e-5f);
  #pragma unroll
  for (int j = 0; j < 12; j++) v[j] = (v[j] - m) * rs * g[l16 + j * 16] + b[l16 + j * 16];
}

// weights fp32 -> bf16 (one-time), 8 elems/thread
__global__ __launch_bounds__(256) void wconv_k(const float* __restrict__ in,
                                               bf16* __restrict__ out, int n8) {
  int i = blockIdx.x * 256 + threadIdx.x;
  if (i < n8) {
    const float4* p = (const float4*)in + (size_t)i * 2;
    float4 a = p[0], b = p[1];
    s8v o;
    o[0] = f2bf(a.x); o[1] = f2bf(a.y); o[2] = f2bf(a.z); o[3] = f2bf(a.w);
    o[4] = f2bf(b.x); o[5] = f2bf(b.y); o[6] = f2bf(b.z); o[7] = f2bf(b.w);
    ((s8v*)out)[i] = o;
  }
}

// src -> act0 (f32), xb = bf16(src), xpb = bf16(src + pos0); 4 elems/thread
__global__ __launch_bounds__(256) void init_k(const float* __restrict__ src,
    const float* __restrict__ pos0, float* __restrict__ a0,
    bf16* __restrict__ xb, bf16* __restrict__ xpb) {
  int i = blockIdx.x * 256 + threadIdx.x;
  float4 s = ((const float4*)src)[i];
  float4 p = ((const float4*)pos0)[i];
  ((float4*)a0)[i] = s;
  s4v ob, op;
  ob[0] = f2bf(s.x); ob[1] = f2bf(s.y); ob[2] = f2bf(s.z); ob[3] = f2bf(s.w);
  op[0] = f2bf(s.x + p.x); op[1] = f2bf(s.y + p.y);
  op[2] = f2bf(s.z + p.z); op[3] = f2bf(s.w + p.w);
  ((s4v*)xb)[i]  = ob;
  ((s4v*)xpb)[i] = op;
}

template<typename TO> __device__ __forceinline__ TO fcast(float v);
template<> __device__ __forceinline__ bf16 fcast<bf16>(float v) { return __float2bfloat16(v); }
template<> __device__ __forceinline__ f16  fcast<f16>(float v)  { return (f16)v; }

// MFMA bf16 GEMM, all-bf16 inputs (pure-copy staging), 2-phase pipeline:
// prefetch tile t+1 into regs before MFMAs of tile t, ONE barrier per K-step.
// Sequential A rows; XCD-chunked swizzle (grid total % 8 == 0).
// C[m, c_off+n] = act( A[row(m), :] @ W[n, :]^T + bias[n] );  A,W bf16 row-major.
template<typename TO, int KT, int BM, int BN, int WM, int WN, bool GELU_ACT>
__global__ __launch_bounds__(WM*WN*64) void bgemm_k(
    const bf16* __restrict__ A, const bf16* __restrict__ W,
    const float* __restrict__ bias, TO* __restrict__ Cmat,
    int ldc, int c_off)
{
  constexpr int NTHR = WM * WN * 64;
  constexpr int LD = 40;               // pad: 80 B row stride -> 2-way alias (free)
  constexpr int MI = BM / (16 * WM);
  constexpr int NJ = BN / (16 * WN);
  constexpr int AC = BM * 4 / NTHR;    // A uint4 chunks / thread / K-step
  constexpr int BC = BN * 4 / NTHR;    // B uint4 chunks
  constexpr int NT = KT / 32;
  static_assert(AC * NTHR == BM * 4 && BC * NTHR == BN * 4, "staging chunks");

  __shared__ short As[2][BM * LD];
  __shared__ short Bs[2][BN * LD];

  const int tid = threadIdx.x;
  const int gx = gridDim.x;
  const int flat = blockIdx.y * gx + blockIdx.x;
  const int chunk = (gx * gridDim.y) >> 3;
  const int work = (flat & 7) * chunk + (flat >> 3);
  const int n0 = (work % gx) * BN;
  const int m0 = (work / gx) * BM;
  const int wave = tid >> 6, lane = tid & 63;
  const int quad = lane >> 4, l16 = lane & 15;
  const int wm = (wave / WN) * (MI * 16);
  const int wn = (wave % WN) * (NJ * 16);

  const bf16* Aptr[AC]; int aoff[AC];
  #pragma unroll
  for (int c = 0; c < AC; c++) {
    int u = tid + c * NTHR;
    int row = u >> 2, c4 = u & 3;
    Aptr[c] = A + (long)(m0 + row) * KT + c4 * 8;
    aoff[c] = row * LD + c4 * 8;
  }
  const bf16* Bptr[BC]; int boff[BC];
  #pragma unroll
  for (int c = 0; c < BC; c++) {
    int u = tid + c * NTHR;
    int row = u >> 2, c4 = u & 3;
    Bptr[c] = W + (long)(n0 + row) * KT + c4 * 8;
    boff[c] = row * LD + c4 * 8;
  }

  uint4 ra[AC], rb[BC];
  #pragma unroll
  for (int c = 0; c < AC; c++) ra[c] = *(const uint4*)(Aptr[c]);
  #pragma unroll
  for (int c = 0; c < BC; c++) rb[c] = *(const uint4*)(Bptr[c]);
  #pragma unroll
  for (int c = 0; c < AC; c++) *(uint4*)&As[0][aoff[c]] = ra[c];
  #pragma unroll
  for (int c = 0; c < BC; c++) *(uint4*)&Bs[0][boff[c]] = rb[c];
  __syncthreads();

  f4v acc[MI][NJ];
  #pragma unroll
  for (int i = 0; i < MI; i++)
    #pragma unroll
    for (int j = 0; j < NJ; j++)
      #pragma unroll
      for (int r = 0; r < 4; r++) acc[i][j][r] = 0.f;

  #pragma unroll
  for (int t = 0; t < NT; t++) {
    const int cur = t & 1;
    if (t + 1 < NT) {
      #pragma unroll
      for (int c = 0; c < AC; c++) ra[c] = *(const uint4*)(Aptr[c] + (t + 1) * 32);
      #pragma unroll
      for (int c = 0; c < BC; c++) rb[c] = *(const uint4*)(Bptr[c] + (t + 1) * 32);
    }
    s8v af[MI], bfv[NJ];
    #pragma unroll
    for (int i = 0; i < MI; i++)
      af[i] = *(const s8v*)&As[cur][(wm + i * 16 + l16) * LD + quad * 8];
    #pragma unroll
    for (int j = 0; j < NJ; j++)
      bfv[j] = *(const s8v*)&Bs[cur][(wn + j * 16 + l16) * LD + quad * 8];
    #pragma unroll
    for (int i = 0; i < MI; i++)
      #pragma unroll
      for (int j = 0; j < NJ; j++)
        acc[i][j] = __builtin_amdgcn_mfma_f32_16x16x32_bf16(af[i], bfv[j], acc[i][j], 0, 0, 0);
    if (t + 1 < NT) {
      #pragma unroll
      for (int c = 0; c < AC; c++) *(uint4*)&As[cur ^ 1][aoff[c]] = ra[c];
      #pragma unroll
      for (int c = 0; c < BC; c++) *(uint4*)&Bs[cur ^ 1][boff[c]] = rb[c];
      __syncthreads();
    }
  }

  #pragma unroll
  for (int j = 0; j < NJ; j++) {
    int gn = n0 + wn + j * 16 + l16;
    float bj = bias[gn];
    #pragma unroll
    for (int i = 0; i < MI; i++) {
      #pragma unroll
      for (int r = 0; r < 4; r++) {
        int gm = m0 + wm + i * 16 + quad * 4 + r;
        float vv = acc[i][j][r] + bj;
        if (GELU_ACT) vv = 0.5f * vv * (1.0f + erff(vv * 0.70710678118654752f));
        Cmat[(long)gm * ldc + c_off + gn] = fcast<TO>(vv);
      }
    }
  }
}

// Fused GEMM + LayerNorm epilogue. Full-width BN=192 (block owns whole rows),
// BM=128, 4 waves (MI=2, NJ=12). A row lives in 16 lanes (quad) x 12 regs.
// EPI=1 (out-proj + LN1):  outf = LN1( xin + (C+bias) );  xbo = bf16(outf).
// EPI=2 (lin2 + LN chain): v = xin + (C+bias); LN(g1); v += identity; LN(g2);
//        if HAS_BLK { v += resid; LN(g3) }; outf = v [outd too]; xbo = bf16(v);
//        xpo = bf16(v + posn). Params staged in LDS once.
template<int KT, int EPI, bool HAS_BLK, bool WRITE_OUT>
__global__ __launch_bounds__(256) void bgemm_ln_k(
    const bf16* __restrict__ A, const bf16* __restrict__ W,
    const float* __restrict__ bias,
    const float* __restrict__ xin, const float* __restrict__ identity,
    const float* __restrict__ resid,
    const float* __restrict__ g1v, const float* __restrict__ b1v,
    const float* __restrict__ g2v, const float* __restrict__ b2v,
    const float* __restrict__ g3v, const float* __restrict__ b3v,
    const float* __restrict__ posn,
    float* __restrict__ outf, float* __restrict__ outd,
    bf16* __restrict__ xbo, bf16* __restrict__ xpo)
{
  constexpr int BM = 128, BN = 192, LD = 40, NTHR = 256;
  constexpr int MI = 2, NJ = 12, AC = 2, BC = 3, NT = KT / 32;
  __shared__ short As[2][BM * LD];
  __shared__ short Bs[2][BN * LD];
  __shared__ float prm[7][192];   // 0=bias 1=g1 2=b1 3=g2 4=b2 5=g3 6=b3

  const int tid = threadIdx.x;
  const int chunk = gridDim.x >> 3;
  const int flat = blockIdx.x;
  const int work = (flat & 7) * chunk + (flat >> 3);   // XCD swizzle
  const int m0 = work * BM;
  const int wave = tid >> 6, lane = tid & 63;
  const int quad = lane >> 4, l16 = lane & 15;
  const int wm = wave * 32;

  if (tid < 192) {
    prm[0][tid] = bias[tid];
    prm[1][tid] = g1v[tid]; prm[2][tid] = b1v[tid];
    if (EPI == 2) {
      prm[3][tid] = g2v[tid]; prm[4][tid] = b2v[tid];
      if (HAS_BLK) { prm[5][tid] = g3v[tid]; prm[6][tid] = b3v[tid]; }
    }
  }

  const bf16* Aptr[AC]; int aoff[AC];
  #pragma unroll
  for (int c = 0; c < AC; c++) {
    int u = tid + c * NTHR;
    int row = u >> 2, c4 = u & 3;
    Aptr[c] = A + (long)(m0 + row) * KT + c4 * 8;
    aoff[c] = row * LD + c4 * 8;
  }
  const bf16* Bptr[BC]; int boff[BC];
  #pragma unroll
  for (int c = 0; c < BC; c++) {
    int u = tid + c * NTHR;
    int row = u >> 2, c4 = u & 3;
    Bptr[c] = W + (long)row * KT + c4 * 8;
    boff[c] = row * LD + c4 * 8;
  }

  uint4 ra[AC], rb[BC];
  #pragma unroll
  for (int c = 0; c < AC; c++) ra[c] = *(const uint4*)(Aptr[c]);
  #pragma unroll
  for (int c = 0; c < BC; c++) rb[c] = *(const uint4*)(Bptr[c]);
  #pragma unroll
  for (int c = 0; c < AC; c++) *(uint4*)&As[0][aoff[c]] = ra[c];
  #pragma unroll
  for (int c = 0; c < BC; c++) *(uint4*)&Bs[0][boff[c]] = rb[c];
  __syncthreads();

  f4v acc[MI][NJ];
  #pragma unroll
  for (int i = 0; i < MI; i++)
    #pragma unroll
    for (int j = 0; j < NJ; j++)
      #pragma unroll
      for (int r = 0; r < 4; r++) acc[i][j][r] = 0.f;

  #pragma unroll
  for (int t = 0; t < NT; t++) {
    const int cur = t & 1;
    if (t + 1 < NT) {
      #pragma unroll
      for (int c = 0; c < AC; c++) ra[c] = *(const uint4*)(Aptr[c] + (t + 1) * 32);
      #pragma unroll
      for (int c = 0; c < BC; c++) rb[c] = *(const uint4*)(Bptr[c] + (t + 1) * 32);
    }
    s8v af[MI], bfv[NJ];
    #pragma unroll
    for (int i = 0; i < MI; i++)
      af[i] = *(const s8v*)&As[cur][(wm + i * 16 + l16) * LD + quad * 8];
    #pragma unroll
    for (int j = 0; j < NJ; j++)
      bfv[j] = *(const s8v*)&Bs[cur][(j * 16 + l16) * LD + quad * 8];
    #pragma unroll
    for (int i = 0; i < MI; i++)
      #pragma unroll
      for (int j = 0; j < NJ; j++)
        acc[i][j] = __builtin_amdgcn_mfma_f32_16x16x32_bf16(af[i], bfv[j], acc[i][j], 0, 0, 0);
    if (t + 1 < NT) {
      #pragma unroll
      for (int c = 0; c < AC; c++) *(uint4*)&As[cur ^ 1][aoff[c]] = ra[c];
      #pragma unroll
      for (int c = 0; c < BC; c++) *(uint4*)&Bs[cur ^ 1][boff[c]] = rb[c];
      __syncthreads();
    }
  }

  // ---- fused LN epilogue (C/D layout: col = l16 + j*16, row = quad*4 + r) ----
  #pragma unroll
  for (int i = 0; i < MI; i++) {
    #pragma unroll
    for (int r = 0; r < 4; r++) {
      long rb_ = (long)(m0 + wm + i * 16 + quad * 4 + r) * 192;
      float v[NJ];
      #pragma unroll
      for (int j = 0; j < NJ; j++) {
        int c = l16 + j * 16;
        v[j] = acc[i][j][r] + prm[0][c] + xin[rb_ + c];
      }
      lnq(v, &prm[1][0], &prm[2][0], l16);
      if (EPI == 2) {
        #pragma unroll
        for (int j = 0; j < NJ; j++) v[j] += identity[rb_ + l16 + j * 16];
        lnq(v, &prm[3][0], &prm[4][0], l16);
        if (HAS_BLK) {
          #pragma unroll
          for (int j = 0; j < NJ; j++) v[j] += resid[rb_ + l16 + j * 16];
          lnq(v, &prm[5][0], &prm[6][0], l16);
        }
      }
      #pragma unroll
      for (int j = 0; j < NJ; j++) {
        int c = l16 + j * 16;
        outf[rb_ + c] = v[j];
        if (WRITE_OUT) outd[rb_ + c] = v[j];
        if (EPI == 1) {
          xbo[rb_ + c] = __float2bfloat16(v[j]);
        } else {
          if (xbo) xbo[rb_ + c] = __float2bfloat16(v[j]);
          if (xpo) xpo[rb_ + c] = __float2bfloat16(v[j] + posn[rb_ + c]);
        }
      }
    }
  }
}

// One block (288 thr) per set; thread = (head, row). qkv [NVOX][576] f16 in
// VOXEL order — this kernel does the permutation: gathers its 36 K/V rows and
// Q row via inds, scatter-writes O back to voxel order (inds is a permutation,
// so each voxel row is written exactly once = reference's first-occurrence).
// Only K,V staged in LDS; Q goes global->regs (packed f16 pairs, no unpack).
// Scores via v_dot2_f32_f16; PV via v_perm pair-transpose + dot2.
// LDS row stride 392 shorts: 784 B rotates 4 banks/row -> 0 conflicts.
#define KLD 392
__global__ __launch_bounds__(288) void attn_set_k(const f16* __restrict__ qkv,
                                                  const int* __restrict__ inds,
                                                  bf16* __restrict__ o)
{
  __shared__ short kv[SS * KLD];   // 28224 B
  __shared__ int si[SS];
  const int s = blockIdx.x;
  const int tid = threadIdx.x;

  if (tid < SS) si[tid] = inds[s * SS + tid];
  __syncthreads();

  const int h = tid / SS;
  const int r = tid - h * SS;
  const int vr = si[r];

  const uint4* qp = (const uint4*)(qkv + (size_t)vr * 576 + h * DH);
  uint4 uq0 = qp[0], uq1 = qp[1], uq2 = qp[2];

  const uint4* gp = (const uint4*)qkv;
  uint4* ls = (uint4*)kv;
  #pragma unroll
  for (int i = 0; i < 6; i++) {
    int u = tid + i * 288;
    int row = u / 48;
    int c = u - row * 48;
    ls[row * 49 + c] = gp[(size_t)si[row] * 72 + 24 + c];
  }
  __syncthreads();

  unsigned qw[12] = { uq0.x, uq0.y, uq0.z, uq0.w,
                      uq1.x, uq1.y, uq1.z, uq1.w,
                      uq2.x, uq2.y, uq2.z, uq2.w };

  const float scale = 0.20412414523193154f;  // 1/sqrt(24)
  float sc[SS];
  #pragma unroll
  for (int l = 0; l < SS; l++) {
    const uint4* kp = (const uint4*)&kv[l * KLD + h * DH];
    uint4 u0 = kp[0], u1 = kp[1], u2 = kp[2];
    float a0 = 0.f, a1 = 0.f, a2 = 0.f;
    a0 = dot2(qw[0], u0.x, a0); a0 = dot2(qw[1], u0.y, a0);
    a0 = dot2(qw[2], u0.z, a0); a0 = dot2(qw[3], u0.w, a0);
    a1 = dot2(qw[4], u1.x, a1); a1 = dot2(qw[5], u1.y, a1);
    a1 = dot2(qw[6], u1.z, a1); a1 = dot2(qw[7], u1.w, a1);
    a2 = dot2(qw[8], u2.x, a2); a2 = dot2(qw[9], u2.y, a2);
    a2 = dot2(qw[10], u2.z, a2); a2 = dot2(qw[11], u2.w, a2);
    sc[l] = (a0 + a1 + a2) * scale;
  }

  float mx = -1e30f;
  #pragma unroll
  for (int l = 0; l < SS; l++) mx = fmaxf(mx, sc[l]);
  float sum = 0.f;
  #pragma unroll
  for (int l = 0; l < SS; l++) { float e = __expf(sc[l] - mx); sc[l] = e; sum += e; }
  float inv = 1.0f / sum;

  float ov[DH];
  #pragma unroll
  for (int d = 0; d < DH; d++) ov[d] = 0.f;
  #pragma unroll
  for (int lp = 0; lp < SS / 2; lp++) {
    const uint4* va = (const uint4*)&kv[(2 * lp) * KLD + 192 + h * DH];
    const uint4* vb = (const uint4*)&kv[(2 * lp + 1) * KLD + 192 + h * DH];
    unsigned pp = pkh(sc[2 * lp], sc[2 * lp + 1]);
    #pragma unroll
    for (int i = 0; i < 3; i++) {
      uint4 ua = va[i], ub = vb[i];
      unsigned wa[4] = { ua.x, ua.y, ua.z, ua.w };
      unsigned wb[4] = { ub.x, ub.y, ub.z, ub.w };
      #pragma unroll
      for (int j = 0; j < 4; j++) {
        unsigned lo = permw(wa[j], wb[j], 0x05040100u);
        unsigned hi = permw(wa[j], wb[j], 0x07060302u);
        ov[8*i + 2*j]     = dot2(pp, lo, ov[8*i + 2*j]);
        ov[8*i + 2*j + 1] = dot2(pp, hi, ov[8*i + 2*j + 1]);
      }
    }
  }

  uint4* op = (uint4*)(o + (size_t)vr * CDIM + h * DH);
  #pragma unroll
  for (int i = 0; i < 3; i++) {
    uint4 u;
    u.x = pack2(ov[8*i+0] * inv, ov[8*i+1] * inv);
    u.y = pack2(ov[8*i+2] * inv, ov[8*i+3] * inv);
    u.z = pack2(ov[8*i+4] * inv, ov[8*i+5] * inv);
    u.w = pack2(ov[8*i+6] * inv, ov[8*i+7] * inv);
    op[i] = u;
  }
}

extern "C" void kernel_launch(void* const* d_in, const int* in_sizes, int n_in,
                              void* d_out, int out_size, void* d_ws, size_t ws_size,
                              hipStream_t stream)
{
  const float* src       = (const float*)d_in[0];
  const float* pos_embed = (const float*)d_in[1];
  const int*   svi       = (const int*)d_in[2];
  /* d_in[3] set_voxel_masks: all-false, unused */
  const float* ipw  = (const float*)d_in[4];
  const float* ipb  = (const float*)d_in[5];
  const float* outw = (const float*)d_in[6];
  const float* outb = (const float*)d_in[7];
  const float* l1w  = (const float*)d_in[8];
  const float* l1b  = (const float*)d_in[9];
  const float* l2w  = (const float*)d_in[10];
  const float* l2b  = (const float*)d_in[11];
  const float* ln1g = (const float*)d_in[12];
  const float* ln1b = (const float*)d_in[13];
  const float* ln2g = (const float*)d_in[14];
  const float* ln2b = (const float*)d_in[15];
  const float* encg = (const float*)d_in[16];
  const float* encb = (const float*)d_in[17];
  const float* blkg = (const float*)d_in[18];
  const float* blkb = (const float*)d_in[19];

  char* w = (char*)d_ws;
  const size_t ACT  = (size_t)NVOX * CDIM * sizeof(float);
  const size_t QKVB = (size_t)NVOX * 576 * sizeof(f16);
  const size_t OB   = (size_t)NVOX * CDIM * sizeof(bf16);
  float* act[3] = { (float*)w, (float*)(w + ACT), (float*)(w + 2 * ACT) };
  f16*  qkv   = (f16*)(w + 3 * ACT);
  bf16* obuf  = (bf16*)(w + 3 * ACT + QKVB);
  bf16* o2buf = (bf16*)(w + 3 * ACT + QKVB + OB);
  // xb uses the o2buf slot (o2 no longer materialized — LN1 fused into out-proj)
  bf16* xb    = o2buf;
  bf16* xpb   = (bf16*)(w + 3 * ACT + QKVB + 2 * OB);   // also x1b (lifetimes disjoint)
  bf16* wbf   = (bf16*)(w + 3 * ACT + QKVB + 3 * OB);
  bf16* wip_b  = wbf;                          // 8 x 576 x 192
  bf16* wout_b = wip_b  + (size_t)8 * 576 * 192;  // 8 x 192 x 192
  bf16* wl1_b  = wout_b + (size_t)8 * 192 * 192;  // 8 x 384 x 192
  bf16* wl2_b  = wl1_b  + (size_t)8 * 384 * 192;  // 8 x 192 x 384
  bf16* hbuf  = (bf16*)qkv;   // reuse after attention (NVOX x 384 fits in NVOX x 576)

  wconv_k<<<(8*576*192/8 + 255)/256, 256, 0, stream>>>(ipw,  wip_b,  8*576*192/8);
  wconv_k<<<(8*192*192/8 + 255)/256, 256, 0, stream>>>(outw, wout_b, 8*192*192/8);
  wconv_k<<<(8*384*192/8 + 255)/256, 256, 0, stream>>>(l1w,  wl1_b,  8*384*192/8);
  wconv_k<<<(8*192*384/8 + 255)/256, 256, 0, stream>>>(l2w,  wl2_b,  8*192*384/8);

  init_k<<<NVOX * CDIM / 4 / 256, 256, 0, stream>>>(src, pos_embed, act[0], xb, xpb);

  int r = 0, ia = 1, ib = 2;
  for (int blkid = 0; blkid < NBLOCKS; blkid++) {
    float* xres = act[r];
    float* cur  = act[r];
    float* outs[2] = { act[ia], act[ib] };
    for (int i = 0; i < 2; i++) {
      int li = blkid * 2 + i;
      int shift = blkid & 1;
      const int* inds = svi + (size_t)(shift * 2 + i) * SETS * SS;
      const float* Bip = ipb + (size_t)li * 576;

      // QK: A = xpb [bf16 x+pos, voxel order], N=384, cols 0..383 of qkv
      bgemm_k<f16, 192, 128, 128, 2, 2, false>
          <<<dim3(3, NVOX / 128), 256, 0, stream>>>(
          xpb, wip_b + (size_t)li * 576 * 192, Bip, qkv, 576, 0);
      // V: A = xb [bf16 x, voxel order], N=192, cols 384..575
      bgemm_k<f16, 192, 128, 64, 4, 1, false>
          <<<dim3(3, NVOX / 128), 256, 0, stream>>>(
          xb, wip_b + (size_t)li * 576 * 192 + (size_t)384 * 192, Bip + 384, qkv,
          576, 384);

      // attn does the permutation: gather K/V/Q rows, scatter O to voxel order
      attn_set_k<<<SETS, 288, 0, stream>>>(qkv, inds, obuf);

      float* x1 = outs[i];
      // out-proj + LN1 fused: x1 = LN1(cur + o2); x1b (=xpb) emitted for lin1
      bgemm_ln_k<192, 1, false, false><<<NVOX / 128, 256, 0, stream>>>(
          obuf, wout_b + (size_t)li * 192 * 192, outb + (size_t)li * 192,
          cur, nullptr, nullptr,
          ln1g + (size_t)li * 192, ln1b + (size_t)li * 192,
          nullptr, nullptr, nullptr, nullptr, nullptr,
          x1, nullptr, xpb /* x1b */, nullptr);

      // lin1: N=384, K=192, GELU; A = x1b bf16 -> hbuf
      bgemm_k<bf16, 192, 128, 128, 2, 2, true>
          <<<dim3(3, NVOX / 128), 256, 0, stream>>>(
          xpb /* x1b */, wl1_b + (size_t)li * 384 * 192, l1b + (size_t)li * 384, hbuf,
          384, 0);

      // lin2 + LN chain fused
      bool isFinal = (blkid == NBLOCKS - 1 && i == 1);
      const float* posn = pos_embed + (size_t)((li + 1) & 1) * NVOX * CDIM;
      const bf16* Al2 = hbuf;
      const bf16* Wl2 = wl2_b + (size_t)li * 192 * 384;
      const float* Bl2 = l2b + (size_t)li * 192;
      if (i == 1) {
        if (isFinal)
          bgemm_ln_k<384, 2, true, true><<<NVOX / 128, 256, 0, stream>>>(
              Al2, Wl2, Bl2, x1, cur, xres,
              ln2g + (size_t)li * 192, ln2b + (size_t)li * 192,
              encg + (size_t)li * 192, encb + (size_t)li * 192,
              blkg + (size_t)blkid * 192, blkb + (size_t)blkid * 192,
              nullptr, x1, (float*)d_out, nullptr, nullptr);
        else
          bgemm_ln_k<384, 2, true, false><<<NVOX / 128, 256, 0, stream>>>(
              Al2, Wl2, Bl2, x1, cur, xres,
              ln2g + (size_t)li * 192, ln2b + (size_t)li * 192,
              encg + (size_t)li * 192, encb + (size_t)li * 192,
              blkg + (size_t)blkid * 192, blkb + (size_t)blkid * 192,
              posn, x1, nullptr, xb, xpb);
      } else {
        bgemm_ln_k<384, 2, false, false><<<NVOX / 128, 256, 0, stream>>>(
            Al2, Wl2, Bl2, x1, cur, nullptr,
            ln2g + (size_t)li * 192, ln2b + (size_t)li * 192,
            encg + (size_t)li * 192, encb + (size_t)li * 192,
            nullptr, nullptr,
            posn, x1, nullptr, xb, xpb);
      }
      cur = x1;
    }
    int newr = ib, na = r, nb = ia;
    r = newr; ia = na; ib = nb;
  }
}

// Round 10
// 2682.012 us; speedup vs baseline: 1.5267x; 1.5267x over previous
//
#include <hip/hip_runtime.h>
#include <hip/hip_bf16.h>
#include <hip/hip_fp16.h>

#define SETS 2048
#define SS   36
#define CDIM 192
#define HEADS 8
#define DH   24
#define FDIM 384
#define NVOX (SETS*SS)   /* 73728 */
#define NBLOCKS 4

typedef __hip_bfloat16 bf16;
typedef _Float16 f16;
typedef __attribute__((ext_vector_type(2))) _Float16 h2v;
typedef __attribute__((ext_vector_type(4))) short s4v;
typedef __attribute__((ext_vector_type(8))) short s8v;
typedef __attribute__((ext_vector_type(4))) float f4v;

__device__ __forceinline__ short f2bf(float x) {
  bf16 h = __float2bfloat16(x);
  return *reinterpret_cast<short*>(&h);
}
__device__ __forceinline__ unsigned pack2(float a, float b) {
  return ((unsigned)(unsigned short)f2bf(a)) | (((unsigned)(unsigned short)f2bf(b)) << 16);
}

// packed f16 dot2 with f32 accumulate: acc + a.lo*b.lo + a.hi*b.hi
__device__ __forceinline__ float dot2(unsigned a, unsigned b, float acc) {
#if __has_builtin(__builtin_amdgcn_fdot2)
  return __builtin_amdgcn_fdot2(__builtin_bit_cast(h2v, a), __builtin_bit_cast(h2v, b), acc, false);
#else
  h2v ha = __builtin_bit_cast(h2v, a), hb = __builtin_bit_cast(h2v, b);
  return acc + (float)ha[0] * (float)hb[0] + (float)ha[1] * (float)hb[1];
#endif
}
// pack two f32 -> packed f16 pair (round-to-zero)
__device__ __forceinline__ unsigned pkh(float a, float b) {
#if __has_builtin(__builtin_amdgcn_cvt_pkrtz)
  return __builtin_bit_cast(unsigned, __builtin_amdgcn_cvt_pkrtz(a, b));
#else
  h2v h; h[0] = (f16)a; h[1] = (f16)b;
  return __builtin_bit_cast(unsigned, h);
#endif
}
// byte-perm: lo-half picks from a, hi-half from b (with our sel constants)
__device__ __forceinline__ unsigned permw(unsigned a, unsigned b, unsigned sel) {
#if __has_builtin(__builtin_amdgcn_perm)
  return __builtin_amdgcn_perm(b, a, sel);
#else
  if (sel == 0x05040100u) return (a & 0xffffu) | (b << 16);
  return (a >> 16) | (b & 0xffff0000u);
#endif
}

// LN over a row held as 12 regs x 16 lanes (quad-local): reduce = 12 adds +
// 4 shfl_xor (xor bits 0-3 stay inside the 16-lane group). g/b from LDS
// (16-lane broadcast pattern, conflict-free). Verified correct in round 9.
__device__ __forceinline__ void lnq(float v[12], const float* g, const float* b, int l16) {
  float s = 0.f;
  #pragma unroll
  for (int j = 0; j < 12; j++) s += v[j];
  #pragma unroll
  for (int off = 8; off > 0; off >>= 1) s += __shfl_xor(s, off);
  float m = s * (1.0f / 192.0f);
  float q = 0.f;
  #pragma unroll
  for (int j = 0; j < 12; j++) { float d = v[j] - m; q += d * d; }
  #pragma unroll
  for (int off = 8; off > 0; off >>= 1) q += __shfl_xor(q, off);
  float rs = rsqrtf(q * (1.0f / 192.0f) + 1e-5f);
  #pragma unroll
  for (int j = 0; j < 12; j++) v[j] = (v[j] - m) * rs * g[l16 + j * 16] + b[l16 + j * 16];
}

// weights fp32 -> bf16 (one-time), 8 elems/thread
__global__ __launch_bounds__(256) void wconv_k(const float* __restrict__ in,
                                               bf16* __restrict__ out, int n8) {
  int i = blockIdx.x * 256 + threadIdx.x;
  if (i < n8) {
    const float4* p = (const float4*)in + (size_t)i * 2;
    float4 a = p[0], b = p[1];
    s8v o;
    o[0] = f2bf(a.x); o[1] = f2bf(a.y); o[2] = f2bf(a.z); o[3] = f2bf(a.w);
    o[4] = f2bf(b.x); o[5] = f2bf(b.y); o[6] = f2bf(b.z); o[7] = f2bf(b.w);
    ((s8v*)out)[i] = o;
  }
}

// src -> act0 (f32), xb = bf16(src), xpb = bf16(src + pos0); 4 elems/thread
__global__ __launch_bounds__(256) void init_k(const float* __restrict__ src,
    const float* __restrict__ pos0, float* __restrict__ a0,
    bf16* __restrict__ xb, bf16* __restrict__ xpb) {
  int i = blockIdx.x * 256 + threadIdx.x;
  float4 s = ((const float4*)src)[i];
  float4 p = ((const float4*)pos0)[i];
  ((float4*)a0)[i] = s;
  s4v ob, op;
  ob[0] = f2bf(s.x); ob[1] = f2bf(s.y); ob[2] = f2bf(s.z); ob[3] = f2bf(s.w);
  op[0] = f2bf(s.x + p.x); op[1] = f2bf(s.y + p.y);
  op[2] = f2bf(s.z + p.z); op[3] = f2bf(s.w + p.w);
  ((s4v*)xb)[i]  = ob;
  ((s4v*)xpb)[i] = op;
}

template<typename TO> __device__ __forceinline__ TO fcast(float v);
template<> __device__ __forceinline__ bf16 fcast<bf16>(float v) { return __float2bfloat16(v); }
template<> __device__ __forceinline__ f16  fcast<f16>(float v)  { return (f16)v; }

// MFMA bf16 GEMM, all-bf16 inputs (pure-copy staging), 2-phase pipeline:
// prefetch tile t+1 into regs before MFMAs of tile t, ONE barrier per K-step.
// Sequential A rows; XCD-chunked swizzle (grid total % 8 == 0).
template<typename TO, int KT, int BM, int BN, int WM, int WN, bool GELU_ACT>
__global__ __launch_bounds__(WM*WN*64) void bgemm_k(
    const bf16* __restrict__ A, const bf16* __restrict__ W,
    const float* __restrict__ bias, TO* __restrict__ Cmat,
    int ldc, int c_off)
{
  constexpr int NTHR = WM * WN * 64;
  constexpr int LD = 40;
  constexpr int MI = BM / (16 * WM);
  constexpr int NJ = BN / (16 * WN);
  constexpr int AC = BM * 4 / NTHR;
  constexpr int BC = BN * 4 / NTHR;
  constexpr int NT = KT / 32;
  static_assert(AC * NTHR == BM * 4 && BC * NTHR == BN * 4, "staging chunks");

  __shared__ short As[2][BM * LD];
  __shared__ short Bs[2][BN * LD];

  const int tid = threadIdx.x;
  const int gx = gridDim.x;
  const int flat = blockIdx.y * gx + blockIdx.x;
  const int chunk = (gx * gridDim.y) >> 3;
  const int work = (flat & 7) * chunk + (flat >> 3);
  const int n0 = (work % gx) * BN;
  const int m0 = (work / gx) * BM;
  const int wave = tid >> 6, lane = tid & 63;
  const int quad = lane >> 4, l16 = lane & 15;
  const int wm = (wave / WN) * (MI * 16);
  const int wn = (wave % WN) * (NJ * 16);

  const bf16* Aptr[AC]; int aoff[AC];
  #pragma unroll
  for (int c = 0; c < AC; c++) {
    int u = tid + c * NTHR;
    int row = u >> 2, c4 = u & 3;
    Aptr[c] = A + (long)(m0 + row) * KT + c4 * 8;
    aoff[c] = row * LD + c4 * 8;
  }
  const bf16* Bptr[BC]; int boff[BC];
  #pragma unroll
  for (int c = 0; c < BC; c++) {
    int u = tid + c * NTHR;
    int row = u >> 2, c4 = u & 3;
    Bptr[c] = W + (long)(n0 + row) * KT + c4 * 8;
    boff[c] = row * LD + c4 * 8;
  }

  uint4 ra[AC], rb[BC];
  #pragma unroll
  for (int c = 0; c < AC; c++) ra[c] = *(const uint4*)(Aptr[c]);
  #pragma unroll
  for (int c = 0; c < BC; c++) rb[c] = *(const uint4*)(Bptr[c]);
  #pragma unroll
  for (int c = 0; c < AC; c++) *(uint4*)&As[0][aoff[c]] = ra[c];
  #pragma unroll
  for (int c = 0; c < BC; c++) *(uint4*)&Bs[0][boff[c]] = rb[c];
  __syncthreads();

  f4v acc[MI][NJ];
  #pragma unroll
  for (int i = 0; i < MI; i++)
    #pragma unroll
    for (int j = 0; j < NJ; j++)
      #pragma unroll
      for (int r = 0; r < 4; r++) acc[i][j][r] = 0.f;

  #pragma unroll
  for (int t = 0; t < NT; t++) {
    const int cur = t & 1;
    if (t + 1 < NT) {
      #pragma unroll
      for (int c = 0; c < AC; c++) ra[c] = *(const uint4*)(Aptr[c] + (t + 1) * 32);
      #pragma unroll
      for (int c = 0; c < BC; c++) rb[c] = *(const uint4*)(Bptr[c] + (t + 1) * 32);
    }
    s8v af[MI], bfv[NJ];
    #pragma unroll
    for (int i = 0; i < MI; i++)
      af[i] = *(const s8v*)&As[cur][(wm + i * 16 + l16) * LD + quad * 8];
    #pragma unroll
    for (int j = 0; j < NJ; j++)
      bfv[j] = *(const s8v*)&Bs[cur][(wn + j * 16 + l16) * LD + quad * 8];
    #pragma unroll
    for (int i = 0; i < MI; i++)
      #pragma unroll
      for (int j = 0; j < NJ; j++)
        acc[i][j] = __builtin_amdgcn_mfma_f32_16x16x32_bf16(af[i], bfv[j], acc[i][j], 0, 0, 0);
    if (t + 1 < NT) {
      #pragma unroll
      for (int c = 0; c < AC; c++) *(uint4*)&As[cur ^ 1][aoff[c]] = ra[c];
      #pragma unroll
      for (int c = 0; c < BC; c++) *(uint4*)&Bs[cur ^ 1][boff[c]] = rb[c];
      __syncthreads();
    }
  }

  #pragma unroll
  for (int j = 0; j < NJ; j++) {
    int gn = n0 + wn + j * 16 + l16;
    float bj = bias[gn];
    #pragma unroll
    for (int i = 0; i < MI; i++) {
      #pragma unroll
      for (int r = 0; r < 4; r++) {
        int gm = m0 + wm + i * 16 + quad * 4 + r;
        float vv = acc[i][j][r] + bj;
        if (GELU_ACT) vv = 0.5f * vv * (1.0f + erff(vv * 0.70710678118654752f));
        Cmat[(long)gm * ldc + c_off + gn] = fcast<TO>(vv);
      }
    }
  }
}

// Fused GEMM + LN epilogue — LEAN shape (round-9 postmortem fix): BM=64,
// 4 waves, WM=4/WN=1 -> MI=1, NJ=12: acc = 48 VGPR (was 96), LDS 46.3 KB
// (was 56.8), __launch_bounds__(256,3) forces >=3 waves/SIMD. Each wave owns
// 16 FULL rows (192 cols in 12 j-frags) -> LN row reduce is quad-local.
// EPI=1 (out-proj + LN1):  outf = LN1( xin + (C+bias) );  xbo = bf16(outf).
// EPI=2 (lin2 + LN chain): v = xin + (C+bias); LN(g1); v += identity; LN(g2);
//   if HAS_BLK { v += resid; LN(g3) }; outf = v [outd]; xbo=bf16(v);
//   xpo = bf16(v + posn). Math identical to round 9 (correctness-verified).
template<int KT, int EPI, bool HAS_BLK, bool WRITE_OUT>
__global__ __launch_bounds__(256, 3) void bgemm_ln_k(
    const bf16* __restrict__ A, const bf16* __restrict__ W,
    const float* __restrict__ bias,
    const float* __restrict__ xin, const float* __restrict__ identity,
    const float* __restrict__ resid,
    const float* __restrict__ g1v, const float* __restrict__ b1v,
    const float* __restrict__ g2v, const float* __restrict__ b2v,
    const float* __restrict__ g3v, const float* __restrict__ b3v,
    const float* __restrict__ posn,
    float* __restrict__ outf, float* __restrict__ outd,
    bf16* __restrict__ xbo, bf16* __restrict__ xpo)
{
  constexpr int BM = 64, LD = 40, NTHR = 256;
  constexpr int NJ = 12, BC = 3, NT = KT / 32;
  __shared__ short As[2][BM * LD];     // 10240 B
  __shared__ short Bs[2][192 * LD];    // 30720 B
  __shared__ float prm[7][192];        //  5376 B

  const int tid = threadIdx.x;
  const int chunk = gridDim.x >> 3;
  const int flat = blockIdx.x;
  const int work = (flat & 7) * chunk + (flat >> 3);   // XCD swizzle
  const int m0 = work * BM;
  const int wave = tid >> 6, lane = tid & 63;
  const int quad = lane >> 4, l16 = lane & 15;
  const int wm = wave * 16;            // each wave owns 16 rows

  if (tid < 192) {
    prm[0][tid] = bias[tid];
    prm[1][tid] = g1v[tid]; prm[2][tid] = b1v[tid];
    if (EPI == 2) {
      prm[3][tid] = g2v[tid]; prm[4][tid] = b2v[tid];
      if (HAS_BLK) { prm[5][tid] = g3v[tid]; prm[6][tid] = b3v[tid]; }
    }
  }

  // A staging: 64 rows x 4 chunks = 256 = 1/thread
  const int arow = tid >> 2, ac4 = tid & 3;
  const bf16* Aptr = A + (long)(m0 + arow) * KT + ac4 * 8;
  const int aoff = arow * LD + ac4 * 8;
  // B staging: 192 rows x 4 chunks = 768 = 3/thread
  const bf16* Bptr[BC]; int boff[BC];
  #pragma unroll
  for (int c = 0; c < BC; c++) {
    int u = tid + c * NTHR;
    int row = u >> 2, c4 = u & 3;
    Bptr[c] = W + (long)row * KT + c4 * 8;
    boff[c] = row * LD + c4 * 8;
  }

  uint4 ra, rb[BC];
  ra = *(const uint4*)(Aptr);
  #pragma unroll
  for (int c = 0; c < BC; c++) rb[c] = *(const uint4*)(Bptr[c]);
  *(uint4*)&As[0][aoff] = ra;
  #pragma unroll
  for (int c = 0; c < BC; c++) *(uint4*)&Bs[0][boff[c]] = rb[c];
  __syncthreads();

  f4v acc[NJ];
  #pragma unroll
  for (int j = 0; j < NJ; j++)
    #pragma unroll
    for (int r = 0; r < 4; r++) acc[j][r] = 0.f;

  #pragma unroll
  for (int t = 0; t < NT; t++) {
    const int cur = t & 1;
    if (t + 1 < NT) {
      ra = *(const uint4*)(Aptr + (t + 1) * 32);
      #pragma unroll
      for (int c = 0; c < BC; c++) rb[c] = *(const uint4*)(Bptr[c] + (t + 1) * 32);
    }
    s8v af = *(const s8v*)&As[cur][(wm + l16) * LD + quad * 8];
    #pragma unroll
    for (int j = 0; j < NJ; j++) {
      s8v bfv = *(const s8v*)&Bs[cur][(j * 16 + l16) * LD + quad * 8];
      acc[j] = __builtin_amdgcn_mfma_f32_16x16x32_bf16(af, bfv, acc[j], 0, 0, 0);
    }
    if (t + 1 < NT) {
      *(uint4*)&As[cur ^ 1][aoff] = ra;
      #pragma unroll
      for (int c = 0; c < BC; c++) *(uint4*)&Bs[cur ^ 1][boff[c]] = rb[c];
      __syncthreads();
    }
  }

  // ---- fused LN epilogue (C/D layout: col = l16 + j*16, row = quad*4 + r) ----
  #pragma unroll
  for (int r = 0; r < 4; r++) {
    long rb_ = (long)(m0 + wm + quad * 4 + r) * 192;
    float v[NJ];
    #pragma unroll
    for (int j = 0; j < NJ; j++) {
      int c = l16 + j * 16;
      v[j] = acc[j][r] + prm[0][c] + xin[rb_ + c];
    }
    lnq(v, &prm[1][0], &prm[2][0], l16);
    if (EPI == 2) {
      #pragma unroll
      for (int j = 0; j < NJ; j++) v[j] += identity[rb_ + l16 + j * 16];
      lnq(v, &prm[3][0], &prm[4][0], l16);
      if (HAS_BLK) {
        #pragma unroll
        for (int j = 0; j < NJ; j++) v[j] += resid[rb_ + l16 + j * 16];
        lnq(v, &prm[5][0], &prm[6][0], l16);
      }
    }
    #pragma unroll
    for (int j = 0; j < NJ; j++) {
      int c = l16 + j * 16;
      outf[rb_ + c] = v[j];
      if (WRITE_OUT) outd[rb_ + c] = v[j];
      if (EPI == 1) {
        xbo[rb_ + c] = __float2bfloat16(v[j]);
      } else {
        if (xbo) xbo[rb_ + c] = __float2bfloat16(v[j]);
        if (xpo) xpo[rb_ + c] = __float2bfloat16(v[j] + posn[rb_ + c]);
      }
    }
  }
}

// One block (288 thr) per set; thread = (head, row). qkv [NVOX][576] f16 in
// VOXEL order — this kernel does the permutation: gathers its 36 K/V rows and
// Q row via inds, scatter-writes O back to voxel order.
#define KLD 392
__global__ __launch_bounds__(288) void attn_set_k(const f16* __restrict__ qkv,
                                                  const int* __restrict__ inds,
                                                  bf16* __restrict__ o)
{
  __shared__ short kv[SS * KLD];   // 28224 B
  __shared__ int si[SS];
  const int s = blockIdx.x;
  const int tid = threadIdx.x;

  if (tid < SS) si[tid] = inds[s * SS + tid];
  __syncthreads();

  const int h = tid / SS;
  const int r = tid - h * SS;
  const int vr = si[r];

  const uint4* qp = (const uint4*)(qkv + (size_t)vr * 576 + h * DH);
  uint4 uq0 = qp[0], uq1 = qp[1], uq2 = qp[2];

  const uint4* gp = (const uint4*)qkv;
  uint4* ls = (uint4*)kv;
  #pragma unroll
  for (int i = 0; i < 6; i++) {
    int u = tid + i * 288;
    int row = u / 48;
    int c = u - row * 48;
    ls[row * 49 + c] = gp[(size_t)si[row] * 72 + 24 + c];
  }
  __syncthreads();

  unsigned qw[12] = { uq0.x, uq0.y, uq0.z, uq0.w,
                      uq1.x, uq1.y, uq1.z, uq1.w,
                      uq2.x, uq2.y, uq2.z, uq2.w };

  const float scale = 0.20412414523193154f;  // 1/sqrt(24)
  float sc[SS];
  #pragma unroll
  for (int l = 0; l < SS; l++) {
    const uint4* kp = (const uint4*)&kv[l * KLD + h * DH];
    uint4 u0 = kp[0], u1 = kp[1], u2 = kp[2];
    float a0 = 0.f, a1 = 0.f, a2 = 0.f;
    a0 = dot2(qw[0], u0.x, a0); a0 = dot2(qw[1], u0.y, a0);
    a0 = dot2(qw[2], u0.z, a0); a0 = dot2(qw[3], u0.w, a0);
    a1 = dot2(qw[4], u1.x, a1); a1 = dot2(qw[5], u1.y, a1);
    a1 = dot2(qw[6], u1.z, a1); a1 = dot2(qw[7], u1.w, a1);
    a2 = dot2(qw[8], u2.x, a2); a2 = dot2(qw[9], u2.y, a2);
    a2 = dot2(qw[10], u2.z, a2); a2 = dot2(qw[11], u2.w, a2);
    sc[l] = (a0 + a1 + a2) * scale;
  }

  float mx = -1e30f;
  #pragma unroll
  for (int l = 0; l < SS; l++) mx = fmaxf(mx, sc[l]);
  float sum = 0.f;
  #pragma unroll
  for (int l = 0; l < SS; l++) { float e = __expf(sc[l] - mx); sc[l] = e; sum += e; }
  float inv = 1.0f / sum;

  float ov[DH];
  #pragma unroll
  for (int d = 0; d < DH; d++) ov[d] = 0.f;
  #pragma unroll
  for (int lp = 0; lp < SS / 2; lp++) {
    const uint4* va = (const uint4*)&kv[(2 * lp) * KLD + 192 + h * DH];
    const uint4* vb = (const uint4*)&kv[(2 * lp + 1) * KLD + 192 + h * DH];
    unsigned pp = pkh(sc[2 * lp], sc[2 * lp + 1]);
    #pragma unroll
    for (int i = 0; i < 3; i++) {
      uint4 ua = va[i], ub = vb[i];
      unsigned wa[4] = { ua.x, ua.y, ua.z, ua.w };
      unsigned wb[4] = { ub.x, ub.y, ub.z, ub.w };
      #pragma unroll
      for (int j = 0; j < 4; j++) {
        unsigned lo = permw(wa[j], wb[j], 0x05040100u);
        unsigned hi = permw(wa[j], wb[j], 0x07060302u);
        ov[8*i + 2*j]     = dot2(pp, lo, ov[8*i + 2*j]);
        ov[8*i + 2*j + 1] = dot2(pp, hi, ov[8*i + 2*j + 1]);
      }
    }
  }

  uint4* op = (uint4*)(o + (size_t)vr * CDIM + h * DH);
  #pragma unroll
  for (int i = 0; i < 3; i++) {
    uint4 u;
    u.x = pack2(ov[8*i+0] * inv, ov[8*i+1] * inv);
    u.y = pack2(ov[8*i+2] * inv, ov[8*i+3] * inv);
    u.z = pack2(ov[8*i+4] * inv, ov[8*i+5] * inv);
    u.w = pack2(ov[8*i+6] * inv, ov[8*i+7] * inv);
    op[i] = u;
  }
}

extern "C" void kernel_launch(void* const* d_in, const int* in_sizes, int n_in,
                              void* d_out, int out_size, void* d_ws, size_t ws_size,
                              hipStream_t stream)
{
  const float* src       = (const float*)d_in[0];
  const float* pos_embed = (const float*)d_in[1];
  const int*   svi       = (const int*)d_in[2];
  /* d_in[3] set_voxel_masks: all-false, unused */
  const float* ipw  = (const float*)d_in[4];
  const float* ipb  = (const float*)d_in[5];
  const float* outw = (const float*)d_in[6];
  const float* outb = (const float*)d_in[7];
  const float* l1w  = (const float*)d_in[8];
  const float* l1b  = (const float*)d_in[9];
  const float* l2w  = (const float*)d_in[10];
  const float* l2b  = (const float*)d_in[11];
  const float* ln1g = (const float*)d_in[12];
  const float* ln1b = (const float*)d_in[13];
  const float* ln2g = (const float*)d_in[14];
  const float* ln2b = (const float*)d_in[15];
  const float* encg = (const float*)d_in[16];
  const float* encb = (const float*)d_in[17];
  const float* blkg = (const float*)d_in[18];
  const float* blkb = (const float*)d_in[19];

  char* w = (char*)d_ws;
  const size_t ACT  = (size_t)NVOX * CDIM * sizeof(float);
  const size_t QKVB = (size_t)NVOX * 576 * sizeof(f16);
  const size_t OB   = (size_t)NVOX * CDIM * sizeof(bf16);
  float* act[3] = { (float*)w, (float*)(w + ACT), (float*)(w + 2 * ACT) };
  f16*  qkv   = (f16*)(w + 3 * ACT);
  bf16* obuf  = (bf16*)(w + 3 * ACT + QKVB);
  bf16* o2buf = (bf16*)(w + 3 * ACT + QKVB + OB);
  // o2 never materialized (LN1 fused into out-proj); slot reused as xb.
  bf16* xb    = o2buf;
  bf16* xpb   = (bf16*)(w + 3 * ACT + QKVB + 2 * OB);   // also x1b (lifetimes disjoint)
  bf16* wbf   = (bf16*)(w + 3 * ACT + QKVB + 3 * OB);
  bf16* wip_b  = wbf;                          // 8 x 576 x 192
  bf16* wout_b = wip_b  + (size_t)8 * 576 * 192;  // 8 x 192 x 192
  bf16* wl1_b  = wout_b + (size_t)8 * 192 * 192;  // 8 x 384 x 192
  bf16* wl2_b  = wl1_b  + (size_t)8 * 384 * 192;  // 8 x 192 x 384
  bf16* hbuf  = (bf16*)qkv;   // reuse after attention (NVOX x 384 fits in NVOX x 576)

  wconv_k<<<(8*576*192/8 + 255)/256, 256, 0, stream>>>(ipw,  wip_b,  8*576*192/8);
  wconv_k<<<(8*192*192/8 + 255)/256, 256, 0, stream>>>(outw, wout_b, 8*192*192/8);
  wconv_k<<<(8*384*192/8 + 255)/256, 256, 0, stream>>>(l1w,  wl1_b,  8*384*192/8);
  wconv_k<<<(8*192*384/8 + 255)/256, 256, 0, stream>>>(l2w,  wl2_b,  8*192*384/8);

  init_k<<<NVOX * CDIM / 4 / 256, 256, 0, stream>>>(src, pos_embed, act[0], xb, xpb);

  int r = 0, ia = 1, ib = 2;
  for (int blkid = 0; blkid < NBLOCKS; blkid++) {
    float* xres = act[r];
    float* cur  = act[r];
    float* outs[2] = { act[ia], act[ib] };
    for (int i = 0; i < 2; i++) {
      int li = blkid * 2 + i;
      int shift = blkid & 1;
      const int* inds = svi + (size_t)(shift * 2 + i) * SETS * SS;
      const float* Bip = ipb + (size_t)li * 576;

      // QK: A = xpb [bf16 x+pos, voxel order], N=384, cols 0..383 of qkv
      bgemm_k<f16, 192, 128, 128, 2, 2, false>
          <<<dim3(3, NVOX / 128), 256, 0, stream>>>(
          xpb, wip_b + (size_t)li * 576 * 192, Bip, qkv, 576, 0);
      // V: A = xb [bf16 x, voxel order], N=192, cols 384..575
      bgemm_k<f16, 192, 128, 64, 4, 1, false>
          <<<dim3(3, NVOX / 128), 256, 0, stream>>>(
          xb, wip_b + (size_t)li * 576 * 192 + (size_t)384 * 192, Bip + 384, qkv,
          576, 384);

      // attn does the permutation: gather K/V/Q rows, scatter O to voxel order
      attn_set_k<<<SETS, 288, 0, stream>>>(qkv, inds, obuf);

      float* x1 = outs[i];
      // out-proj + LN1 fused (lean): x1 = LN1(cur + o2); x1b (=xpb) for lin1
      bgemm_ln_k<192, 1, false, false><<<NVOX / 64, 256, 0, stream>>>(
          obuf, wout_b + (size_t)li * 192 * 192, outb + (size_t)li * 192,
          cur, nullptr, nullptr,
          ln1g + (size_t)li * 192, ln1b + (size_t)li * 192,
          nullptr, nullptr, nullptr, nullptr, nullptr,
          x1, nullptr, xpb /* x1b */, nullptr);

      // lin1: N=384, K=192, GELU; A = x1b bf16 -> hbuf
      bgemm_k<bf16, 192, 128, 128, 2, 2, true>
          <<<dim3(3, NVOX / 128), 256, 0, stream>>>(
          xpb /* x1b */, wl1_b + (size_t)li * 384 * 192, l1b + (size_t)li * 384, hbuf,
          384, 0);

      // lin2 + LN chain fused (lean)
      bool isFinal = (blkid == NBLOCKS - 1 && i == 1);
      const float* posn = pos_embed + (size_t)((li + 1) & 1) * NVOX * CDIM;
      const bf16* Al2 = hbuf;
      const bf16* Wl2 = wl2_b + (size_t)li * 192 * 384;
      const float* Bl2 = l2b + (size_t)li * 192;
      if (i == 1) {
        if (isFinal)
          bgemm_ln_k<384, 2, true, true><<<NVOX / 64, 256, 0, stream>>>(
              Al2, Wl2, Bl2, x1, cur, xres,
              ln2g + (size_t)li * 192, ln2b + (size_t)li * 192,
              encg + (size_t)li * 192, encb + (size_t)li * 192,
              blkg + (size_t)blkid * 192, blkb + (size_t)blkid * 192,
              nullptr, x1, (float*)d_out, nullptr, nullptr);
        else
          bgemm_ln_k<384, 2, true, false><<<NVOX / 64, 256, 0, stream>>>(
              Al2, Wl2, Bl2, x1, cur, xres,
              ln2g + (size_t)li * 192, ln2b + (size_t)li * 192,
              encg + (size_t)li * 192, encb + (size_t)li * 192,
              blkg + (size_t)blkid * 192, blkb + (size_t)blkid * 192,
              posn, x1, nullptr, xb, xpb);
      } else {
        bgemm_ln_k<384, 2, false, false><<<NVOX / 64, 256, 0, stream>>>(
            Al2, Wl2, Bl2, x1, cur, nullptr,
            ln2g + (size_t)li * 192, ln2b + (size_t)li * 192,
            encg + (size_t)li * 192, encb + (size_t)li * 192,
            nullptr, nullptr,
            posn, x1, nullptr, xb, xpb);
      }
      cur = x1;
    }
    int newr = ib, na = r, nb = ia;
    r = newr; ia = na; ib = nb;
  }
}

// Round 11
// 2466.235 us; speedup vs baseline: 1.6602x; 1.0875x over previous
//
#include <hip/hip_runtime.h>
#include <hip/hip_bf16.h>
#include <hip/hip_fp16.h>

#define SETS 2048
#define SS   36
#define CDIM 192
#define HEADS 8
#define DH   24
#define FDIM 384
#define NVOX (SETS*SS)   /* 73728 */
#define NBLOCKS 4

typedef __hip_bfloat16 bf16;
typedef _Float16 f16;
typedef __attribute__((ext_vector_type(2))) _Float16 h2v;
typedef __attribute__((ext_vector_type(4))) short s4v;
typedef __attribute__((ext_vector_type(8))) short s8v;
typedef __attribute__((ext_vector_type(4))) float f4v;

__device__ __forceinline__ float to_f(float x) { return x; }
__device__ __forceinline__ float to_f(bf16 x)  { return __bfloat162float(x); }

__device__ __forceinline__ short f2bf(float x) {
  bf16 h = __float2bfloat16(x);
  return *reinterpret_cast<short*>(&h);
}
__device__ __forceinline__ unsigned pack2(float a, float b) {
  return ((unsigned)(unsigned short)f2bf(a)) | (((unsigned)(unsigned short)f2bf(b)) << 16);
}

// packed f16 dot2 with f32 accumulate: acc + a.lo*b.lo + a.hi*b.hi
__device__ __forceinline__ float dot2(unsigned a, unsigned b, float acc) {
#if __has_builtin(__builtin_amdgcn_fdot2)
  return __builtin_amdgcn_fdot2(__builtin_bit_cast(h2v, a), __builtin_bit_cast(h2v, b), acc, false);
#else
  h2v ha = __builtin_bit_cast(h2v, a), hb = __builtin_bit_cast(h2v, b);
  return acc + (float)ha[0] * (float)hb[0] + (float)ha[1] * (float)hb[1];
#endif
}
// pack two f32 -> packed f16 pair (round-to-zero)
__device__ __forceinline__ unsigned pkh(float a, float b) {
#if __has_builtin(__builtin_amdgcn_cvt_pkrtz)
  return __builtin_bit_cast(unsigned, __builtin_amdgcn_cvt_pkrtz(a, b));
#else
  h2v h; h[0] = (f16)a; h[1] = (f16)b;
  return __builtin_bit_cast(unsigned, h);
#endif
}
// byte-perm: lo-half picks from a, hi-half from b (with our sel constants)
__device__ __forceinline__ unsigned permw(unsigned a, unsigned b, unsigned sel) {
#if __has_builtin(__builtin_amdgcn_perm)
  return __builtin_amdgcn_perm(b, a, sel);
#else
  if (sel == 0x05040100u) return (a & 0xffffu) | (b << 16);
  return (a >> 16) | (b & 0xffff0000u);
#endif
}

__device__ __forceinline__ float allreduce64(float v) {
  #pragma unroll
  for (int off = 32; off > 0; off >>= 1) v += __shfl_xor(v, off);
  return v;
}

// LayerNorm over 192 channels held as 3 values/lane (c = t, t+64, t+128)
__device__ __forceinline__ void ln3(float v[3], const float* g, const float* b, int t) {
  float s = allreduce64(v[0] + v[1] + v[2]);
  float m = s * (1.0f / 192.0f);
  float d0 = v[0] - m, d1 = v[1] - m, d2 = v[2] - m;
  float q = allreduce64(d0 * d0 + d1 * d1 + d2 * d2);
  float rs = rsqrtf(q * (1.0f / 192.0f) + 1e-5f);
  v[0] = d0 * rs * g[t]       + b[t];
  v[1] = d1 * rs * g[t + 64]  + b[t + 64];
  v[2] = d2 * rs * g[t + 128] + b[t + 128];
}

// fp32 -> bf16 bulk convert (weights, pos planes), 8 elems/thread
__global__ __launch_bounds__(256) void wconv_k(const float* __restrict__ in,
                                               bf16* __restrict__ out, int n8) {
  int i = blockIdx.x * 256 + threadIdx.x;
  if (i < n8) {
    const float4* p = (const float4*)in + (size_t)i * 2;
    float4 a = p[0], b = p[1];
    s8v o;
    o[0] = f2bf(a.x); o[1] = f2bf(a.y); o[2] = f2bf(a.z); o[3] = f2bf(a.w);
    o[4] = f2bf(b.x); o[5] = f2bf(b.y); o[6] = f2bf(b.z); o[7] = f2bf(b.w);
    ((s8v*)out)[i] = o;
  }
}

// src -> act0 (f32), xb = bf16(src), xpb = bf16(src + pos0); 4 elems/thread
__global__ __launch_bounds__(256) void init_k(const float* __restrict__ src,
    const float* __restrict__ pos0, float* __restrict__ a0,
    bf16* __restrict__ xb, bf16* __restrict__ xpb) {
  int i = blockIdx.x * 256 + threadIdx.x;
  float4 s = ((const float4*)src)[i];
  float4 p = ((const float4*)pos0)[i];
  ((float4*)a0)[i] = s;
  s4v ob, op;
  ob[0] = f2bf(s.x); ob[1] = f2bf(s.y); ob[2] = f2bf(s.z); ob[3] = f2bf(s.w);
  op[0] = f2bf(s.x + p.x); op[1] = f2bf(s.y + p.y);
  op[2] = f2bf(s.z + p.z); op[3] = f2bf(s.w + p.w);
  ((s4v*)xb)[i]  = ob;
  ((s4v*)xpb)[i] = op;
}

template<typename TO> __device__ __forceinline__ TO fcast(float v);
template<> __device__ __forceinline__ bf16 fcast<bf16>(float v) { return __float2bfloat16(v); }
template<> __device__ __forceinline__ f16  fcast<f16>(float v)  { return (f16)v; }

// MFMA bf16 GEMM, all-bf16 inputs (pure-copy staging), 2-phase pipeline:
// prefetch tile t+1 into regs before MFMAs of tile t, ONE barrier per K-step.
// Sequential A rows (no gather — the permutation lives in attn_set_k).
// XCD-chunked swizzle: grid must satisfy (gx*gy)%8==0 (all ours are 1728).
// C[m, c_off+n] = act( A[row(m), :] @ W[n, :]^T + bias[n] );  A,W bf16 row-major.
template<typename TO, int KT, int BM, int BN, int WM, int WN, bool GELU_ACT>
__global__ __launch_bounds__(WM*WN*64) void bgemm_k(
    const bf16* __restrict__ A, const bf16* __restrict__ W,
    const float* __restrict__ bias, TO* __restrict__ Cmat,
    int ldc, int c_off)
{
  constexpr int NTHR = WM * WN * 64;
  constexpr int LD = 40;               // pad: 80 B row stride -> 2-way alias (free)
  constexpr int MI = BM / (16 * WM);
  constexpr int NJ = BN / (16 * WN);
  constexpr int AC = BM * 4 / NTHR;    // A uint4 chunks / thread / K-step
  constexpr int BC = BN * 4 / NTHR;    // B uint4 chunks
  constexpr int NT = KT / 32;
  static_assert(AC * NTHR == BM * 4 && BC * NTHR == BN * 4, "staging chunks");

  __shared__ short As[2][BM * LD];
  __shared__ short Bs[2][BN * LD];

  const int tid = threadIdx.x;
  const int gx = gridDim.x;
  const int flat = blockIdx.y * gx + blockIdx.x;
  const int chunk = (gx * gridDim.y) >> 3;
  const int work = (flat & 7) * chunk + (flat >> 3);
  const int n0 = (work % gx) * BN;
  const int m0 = (work / gx) * BM;
  const int wave = tid >> 6, lane = tid & 63;
  const int quad = lane >> 4, l16 = lane & 15;
  const int wm = (wave / WN) * (MI * 16);
  const int wn = (wave % WN) * (NJ * 16);

  const bf16* Aptr[AC]; int aoff[AC];
  #pragma unroll
  for (int c = 0; c < AC; c++) {
    int u = tid + c * NTHR;
    int row = u >> 2, c4 = u & 3;
    Aptr[c] = A + (long)(m0 + row) * KT + c4 * 8;
    aoff[c] = row * LD + c4 * 8;
  }
  const bf16* Bptr[BC]; int boff[BC];
  #pragma unroll
  for (int c = 0; c < BC; c++) {
    int u = tid + c * NTHR;
    int row = u >> 2, c4 = u & 3;
    Bptr[c] = W + (long)(n0 + row) * KT + c4 * 8;
    boff[c] = row * LD + c4 * 8;
  }

  uint4 ra[AC], rb[BC];
  #pragma unroll
  for (int c = 0; c < AC; c++) ra[c] = *(const uint4*)(Aptr[c]);
  #pragma unroll
  for (int c = 0; c < BC; c++) rb[c] = *(const uint4*)(Bptr[c]);
  #pragma unroll
  for (int c = 0; c < AC; c++) *(uint4*)&As[0][aoff[c]] = ra[c];
  #pragma unroll
  for (int c = 0; c < BC; c++) *(uint4*)&Bs[0][boff[c]] = rb[c];
  __syncthreads();

  f4v acc[MI][NJ];
  #pragma unroll
  for (int i = 0; i < MI; i++)
    #pragma unroll
    for (int j = 0; j < NJ; j++)
      #pragma unroll
      for (int r = 0; r < 4; r++) acc[i][j][r] = 0.f;

  #pragma unroll
  for (int t = 0; t < NT; t++) {
    const int cur = t & 1;
    if (t + 1 < NT) {                     // issue next-tile loads (in flight during MFMA)
      #pragma unroll
      for (int c = 0; c < AC; c++) ra[c] = *(const uint4*)(Aptr[c] + (t + 1) * 32);
      #pragma unroll
      for (int c = 0; c < BC; c++) rb[c] = *(const uint4*)(Bptr[c] + (t + 1) * 32);
    }
    s8v af[MI], bfv[NJ];
    #pragma unroll
    for (int i = 0; i < MI; i++)
      af[i] = *(const s8v*)&As[cur][(wm + i * 16 + l16) * LD + quad * 8];
    #pragma unroll
    for (int j = 0; j < NJ; j++)
      bfv[j] = *(const s8v*)&Bs[cur][(wn + j * 16 + l16) * LD + quad * 8];
    #pragma unroll
    for (int i = 0; i < MI; i++)
      #pragma unroll
      for (int j = 0; j < NJ; j++)
        acc[i][j] = __builtin_amdgcn_mfma_f32_16x16x32_bf16(af[i], bfv[j], acc[i][j], 0, 0, 0);
    if (t + 1 < NT) {                     // write next tile to the other buffer
      #pragma unroll
      for (int c = 0; c < AC; c++) *(uint4*)&As[cur ^ 1][aoff[c]] = ra[c];
      #pragma unroll
      for (int c = 0; c < BC; c++) *(uint4*)&Bs[cur ^ 1][boff[c]] = rb[c];
      __syncthreads();                    // single barrier per K-step
    }
  }

  #pragma unroll
  for (int j = 0; j < NJ; j++) {
    int gn = n0 + wn + j * 16 + l16;
    float bj = bias[gn];
    #pragma unroll
    for (int i = 0; i < MI; i++) {
      #pragma unroll
      for (int r = 0; r < 4; r++) {
        int gm = m0 + wm + i * 16 + quad * 4 + r;
        float vv = acc[i][j][r] + bj;
        if (GELU_ACT) vv = 0.5f * vv * (1.0f + erff(vv * 0.70710678118654752f));
        Cmat[(long)gm * ldc + c_off + gn] = fcast<TO>(vv);
      }
    }
  }
}

// One block (288 thr) per set; thread = (head, row). qkv [NVOX][576] f16 in
// VOXEL order — this kernel does the permutation: gathers its 36 K/V rows and
// Q row via inds, scatter-writes O back to voxel order (inds is a permutation,
// so each voxel row is written exactly once = reference's first-occurrence).
// Only K,V staged in LDS; Q goes global->regs (packed f16 pairs, no unpack).
// Scores via v_dot2_f32_f16; PV via v_perm pair-transpose + dot2.
// LDS row stride 392 shorts: 784 B rotates 4 banks/row -> 0 conflicts.
#define KLD 392
__global__ __launch_bounds__(288) void attn_set_k(const f16* __restrict__ qkv,
                                                  const int* __restrict__ inds,
                                                  bf16* __restrict__ o)
{
  __shared__ short kv[SS * KLD];   // 28224 B
  __shared__ int si[SS];
  const int s = blockIdx.x;
  const int tid = threadIdx.x;

  if (tid < SS) si[tid] = inds[s * SS + tid];
  __syncthreads();

  const int h = tid / SS;
  const int r = tid - h * SS;
  const int vr = si[r];

  // ---- q row -> registers, packed (48 B/thread, gathered row) ----
  const uint4* qp = (const uint4*)(qkv + (size_t)vr * 576 + h * DH);
  uint4 uq0 = qp[0], uq1 = qp[1], uq2 = qp[2];

  // ---- stage K,V: 36 gathered rows x 48 uint4 (cols 192..575), 6/thread ----
  const uint4* gp = (const uint4*)qkv;
  uint4* ls = (uint4*)kv;
  #pragma unroll
  for (int i = 0; i < 6; i++) {
    int u = tid + i * 288;
    int row = u / 48;
    int c = u - row * 48;
    ls[row * 49 + c] = gp[(size_t)si[row] * 72 + 24 + c];
  }
  __syncthreads();

  unsigned qw[12] = { uq0.x, uq0.y, uq0.z, uq0.w,
                      uq1.x, uq1.y, uq1.z, uq1.w,
                      uq2.x, uq2.y, uq2.z, uq2.w };

  // ---- scores: K at kv cols 0..191, 12 dot2 per row ----
  const float scale = 0.20412414523193154f;  // 1/sqrt(24)
  float sc[SS];
  #pragma unroll
  for (int l = 0; l < SS; l++) {
    const uint4* kp = (const uint4*)&kv[l * KLD + h * DH];
    uint4 u0 = kp[0], u1 = kp[1], u2 = kp[2];
    float a0 = 0.f, a1 = 0.f, a2 = 0.f;     // 3 chains for ILP
    a0 = dot2(qw[0], u0.x, a0); a0 = dot2(qw[1], u0.y, a0);
    a0 = dot2(qw[2], u0.z, a0); a0 = dot2(qw[3], u0.w, a0);
    a1 = dot2(qw[4], u1.x, a1); a1 = dot2(qw[5], u1.y, a1);
    a1 = dot2(qw[6], u1.z, a1); a1 = dot2(qw[7], u1.w, a1);
    a2 = dot2(qw[8], u2.x, a2); a2 = dot2(qw[9], u2.y, a2);
    a2 = dot2(qw[10], u2.z, a2); a2 = dot2(qw[11], u2.w, a2);
    sc[l] = (a0 + a1 + a2) * scale;
  }

  // ---- softmax (per-thread, registers; normalization deferred) ----
  float mx = -1e30f;
  #pragma unroll
  for (int l = 0; l < SS; l++) mx = fmaxf(mx, sc[l]);
  float sum = 0.f;
  #pragma unroll
  for (int l = 0; l < SS; l++) { float e = __expf(sc[l] - mx); sc[l] = e; sum += e; }
  float inv = 1.0f / sum;

  // ---- P @ V: V rows in pairs; perm pair-transpose + dot2 ----
  float ov[DH];
  #pragma unroll
  for (int d = 0; d < DH; d++) ov[d] = 0.f;
  #pragma unroll
  for (int lp = 0; lp < SS / 2; lp++) {
    const uint4* va = (const uint4*)&kv[(2 * lp) * KLD + 192 + h * DH];
    const uint4* vb = (const uint4*)&kv[(2 * lp + 1) * KLD + 192 + h * DH];
    unsigned pp = pkh(sc[2 * lp], sc[2 * lp + 1]);
    #pragma unroll
    for (int i = 0; i < 3; i++) {
      uint4 ua = va[i], ub = vb[i];
      unsigned wa[4] = { ua.x, ua.y, ua.z, ua.w };
      unsigned wb[4] = { ub.x, ub.y, ub.z, ub.w };
      #pragma unroll
      for (int j = 0; j < 4; j++) {
        unsigned lo = permw(wa[j], wb[j], 0x05040100u);  // (Va[2j],   Vb[2j])
        unsigned hi = permw(wa[j], wb[j], 0x07060302u);  // (Va[2j+1], Vb[2j+1])
        ov[8*i + 2*j]     = dot2(pp, lo, ov[8*i + 2*j]);
        ov[8*i + 2*j + 1] = dot2(pp, hi, ov[8*i + 2*j + 1]);
      }
    }
  }

  // ---- scatter-write o to voxel row vr (48 B contiguous per thread) ----
  uint4* op = (uint4*)(o + (size_t)vr * CDIM + h * DH);
  #pragma unroll
  for (int i = 0; i < 3; i++) {
    uint4 u;
    u.x = pack2(ov[8*i+0] * inv, ov[8*i+1] * inv);
    u.y = pack2(ov[8*i+2] * inv, ov[8*i+3] * inv);
    u.z = pack2(ov[8*i+4] * inv, ov[8*i+5] * inv);
    u.w = pack2(ov[8*i+6] * inv, ov[8*i+7] * inv);
    op[i] = u;
  }
}

// x1[p] = LN( x_in[p] + o2[p] ); also bf16 copy x1b. Pure streaming (o2 is in
// voxel order). 4 rows/block (1 per wave). [round-7 shape — best measured]
__global__ __launch_bounds__(256) void ln1_k(
    const float* __restrict__ xin, const bf16* __restrict__ o2,
    const float* __restrict__ g, const float* __restrict__ b,
    float* __restrict__ x1, bf16* __restrict__ x1b)
{
  int p = blockIdx.x * 4 + (threadIdx.x >> 6);
  int t = threadIdx.x & 63;
  long base = (long)p * 192;
  float v[3];
  #pragma unroll
  for (int j = 0; j < 3; j++) { int c = t + 64 * j; v[j] = xin[base + c] + to_f(o2[base + c]); }
  ln3(v, g, b, t);
  #pragma unroll
  for (int j = 0; j < 3; j++) {
    int c = t + 64 * j;
    x1[base + c]  = v[j];
    x1b[base + c] = __float2bfloat16(v[j]);
  }
}

// out = LN( LN( LN(x1+ff, ln2) + identity, enc) [+resid, blk] ), 4 rows/block.
// Emits bf16 x (xbo) and bf16 x+pos_next (xpo) for the next layer's GEMMs.
// posn is PRE-CONVERTED bf16 (r11: saves 28.3 MB of f32 pos reads per call;
// result is rounded to bf16 anyway -> <=1 ulp difference).
template<bool HAS_BLK, bool WRITE_OUT>
__global__ __launch_bounds__(256) void ln_chain_k(
    const float* __restrict__ x1, const bf16* __restrict__ ff,
    const float* __restrict__ identity, const float* __restrict__ resid,
    const float* __restrict__ g2, const float* __restrict__ b2,
    const float* __restrict__ ge, const float* __restrict__ be,
    const float* __restrict__ gb, const float* __restrict__ bb,
    float* __restrict__ outf, float* __restrict__ outd,
    const bf16* __restrict__ posn, bf16* __restrict__ xbo,
    bf16* __restrict__ xpo)
{
  int row = blockIdx.x * 4 + (threadIdx.x >> 6);
  int t = threadIdx.x & 63;
  long base = (long)row * 192;
  float v[3];
  #pragma unroll
  for (int j = 0; j < 3; j++) { int c = t + 64 * j; v[j] = x1[base + c] + to_f(ff[base + c]); }
  ln3(v, g2, b2, t);
  #pragma unroll
  for (int j = 0; j < 3; j++) { int c = t + 64 * j; v[j] += identity[base + c]; }
  ln3(v, ge, be, t);
  if (HAS_BLK) {
    #pragma unroll
    for (int j = 0; j < 3; j++) { int c = t + 64 * j; v[j] += resid[base + c]; }
    ln3(v, gb, bb, t);
  }
  #pragma unroll
  for (int j = 0; j < 3; j++) {
    int c = t + 64 * j;
    outf[base + c] = v[j];
    if (WRITE_OUT) outd[base + c] = v[j];
  }
  if (xbo) {
    #pragma unroll
    for (int j = 0; j < 3; j++) { int c = t + 64 * j; xbo[base + c] = __float2bfloat16(v[j]); }
  }
  if (xpo) {
    #pragma unroll
    for (int j = 0; j < 3; j++) {
      int c = t + 64 * j;
      xpo[base + c] = __float2bfloat16(v[j] + to_f(posn[base + c]));
    }
  }
}

extern "C" void kernel_launch(void* const* d_in, const int* in_sizes, int n_in,
                              void* d_out, int out_size, void* d_ws, size_t ws_size,
                              hipStream_t stream)
{
  const float* src       = (const float*)d_in[0];
  const float* pos_embed = (const float*)d_in[1];
  const int*   svi       = (const int*)d_in[2];
  /* d_in[3] set_voxel_masks: all-false, unused */
  const float* ipw  = (const float*)d_in[4];
  const float* ipb  = (const float*)d_in[5];
  const float* outw = (const float*)d_in[6];
  const float* outb = (const float*)d_in[7];
  const float* l1w  = (const float*)d_in[8];
  const float* l1b  = (const float*)d_in[9];
  const float* l2w  = (const float*)d_in[10];
  const float* l2b  = (const float*)d_in[11];
  const float* ln1g = (const float*)d_in[12];
  const float* ln1b = (const float*)d_in[13];
  const float* ln2g = (const float*)d_in[14];
  const float* ln2b = (const float*)d_in[15];
  const float* encg = (const float*)d_in[16];
  const float* encb = (const float*)d_in[17];
  const float* blkg = (const float*)d_in[18];
  const float* blkb = (const float*)d_in[19];

  char* w = (char*)d_ws;
  const size_t ACT  = (size_t)NVOX * CDIM * sizeof(float);
  const size_t QKVB = (size_t)NVOX * 576 * sizeof(f16);
  const size_t OB   = (size_t)NVOX * CDIM * sizeof(bf16);
  float* act[3] = { (float*)w, (float*)(w + ACT), (float*)(w + 2 * ACT) };
  f16*  qkv   = (f16*)(w + 3 * ACT);
  bf16* obuf  = (bf16*)(w + 3 * ACT + QKVB);
  bf16* o2buf = (bf16*)(w + 3 * ACT + QKVB + OB);
  // xb ALIASES o2buf: per-layer order is V-reads-xb -> out-proj-writes-o2buf ->
  // ln1-reads-o2buf -> ln_chain-writes-xb; never concurrent.
  bf16* xb    = o2buf;
  bf16* xpb   = (bf16*)(w + 3 * ACT + QKVB + 2 * OB);   // also x1b (lifetimes disjoint)
  bf16* wbf   = (bf16*)(w + 3 * ACT + QKVB + 3 * OB);
  bf16* wip_b  = wbf;                          // 8 x 576 x 192
  bf16* wout_b = wip_b  + (size_t)8 * 576 * 192;  // 8 x 192 x 192
  bf16* wl1_b  = wout_b + (size_t)8 * 192 * 192;  // 8 x 384 x 192
  bf16* wl2_b  = wl1_b  + (size_t)8 * 384 * 192;  // 8 x 192 x 384
  bf16* posb   = wl2_b  + (size_t)8 * 192 * 384;  // 2 x NVOX x 192 (bf16 pos)
  bf16* hbuf  = (bf16*)qkv;   // reuse after attention (NVOX x 384 fits in NVOX x 576)
  bf16* ffbuf = obuf;         // reuse after out-proj

  // one-time conversions fp32 -> bf16 (weights + both pos planes)
  wconv_k<<<(8*576*192/8 + 255)/256, 256, 0, stream>>>(ipw,  wip_b,  8*576*192/8);
  wconv_k<<<(8*192*192/8 + 255)/256, 256, 0, stream>>>(outw, wout_b, 8*192*192/8);
  wconv_k<<<(8*384*192/8 + 255)/256, 256, 0, stream>>>(l1w,  wl1_b,  8*384*192/8);
  wconv_k<<<(8*192*384/8 + 255)/256, 256, 0, stream>>>(l2w,  wl2_b,  8*192*384/8);
  wconv_k<<<(2*NVOX*192/8 + 255)/256, 256, 0, stream>>>(pos_embed, posb, 2*NVOX*192/8);

  init_k<<<NVOX * CDIM / 4 / 256, 256, 0, stream>>>(src, pos_embed, act[0], xb, xpb);

  int r = 0, ia = 1, ib = 2;
  for (int blkid = 0; blkid < NBLOCKS; blkid++) {
    int shift = blkid & 1;
    float* xres = act[r];
    float* cur  = act[r];
    float* outs[2] = { act[ia], act[ib] };
    for (int i = 0; i < 2; i++) {
      int li = blkid * 2 + i;
      const int* inds = svi + (size_t)(shift * 2 + i) * SETS * SS;
      const float* Bip = ipb + (size_t)li * 576;

      // QK: A = xpb [bf16 x+pos, voxel order], N=384, cols 0..383 of qkv
      bgemm_k<f16, 192, 128, 128, 2, 2, false>
          <<<dim3(3, NVOX / 128), 256, 0, stream>>>(
          xpb, wip_b + (size_t)li * 576 * 192, Bip, qkv, 576, 0);
      // V: A = xb [bf16 x, voxel order], N=192, cols 384..575
      bgemm_k<f16, 192, 128, 64, 4, 1, false>
          <<<dim3(3, NVOX / 128), 256, 0, stream>>>(
          xb, wip_b + (size_t)li * 576 * 192 + (size_t)384 * 192, Bip + 384, qkv,
          576, 384);

      // attn does the permutation: gather K/V/Q rows, scatter O to voxel order
      attn_set_k<<<SETS, 288, 0, stream>>>(qkv, inds, obuf);

      // out-proj: N=192, K=192, A = obuf bf16 (voxel order)
      bgemm_k<bf16, 192, 128, 64, 4, 1, false>
          <<<dim3(3, NVOX / 128), 256, 0, stream>>>(
          obuf, wout_b + (size_t)li * 192 * 192, outb + (size_t)li * 192, o2buf,
          192, 0);

      float* x1 = outs[i];
      ln1_k<<<NVOX / 4, 256, 0, stream>>>(cur, o2buf,
          ln1g + (size_t)li * 192, ln1b + (size_t)li * 192, x1, xpb /* = x1b */);

      // lin1: N=384, K=192, GELU; A = x1b bf16
      bgemm_k<bf16, 192, 128, 128, 2, 2, true>
          <<<dim3(3, NVOX / 128), 256, 0, stream>>>(
          xpb /* x1b */, wl1_b + (size_t)li * 384 * 192, l1b + (size_t)li * 384, hbuf,
          384, 0);
      // lin2: N=192, K=384, A = hbuf bf16
      bgemm_k<bf16, 384, 128, 64, 4, 1, false>
          <<<dim3(3, NVOX / 128), 256, 0, stream>>>(
          hbuf, wl2_b + (size_t)li * 192 * 384, l2b + (size_t)li * 192, ffbuf,
          192, 0);

      bool isFinal = (blkid == NBLOCKS - 1 && i == 1);
      const bf16* posn = posb + (size_t)((li + 1) & 1) * NVOX * CDIM;
      if (i == 1) {
        if (isFinal)
          ln_chain_k<true, true><<<NVOX / 4, 256, 0, stream>>>(x1, ffbuf, cur, xres,
              ln2g + (size_t)li * 192, ln2b + (size_t)li * 192,
              encg + (size_t)li * 192, encb + (size_t)li * 192,
              blkg + (size_t)blkid * 192, blkb + (size_t)blkid * 192,
              x1, (float*)d_out, nullptr, nullptr, nullptr);
        else
          ln_chain_k<true, false><<<NVOX / 4, 256, 0, stream>>>(x1, ffbuf, cur, xres,
              ln2g + (size_t)li * 192, ln2b + (size_t)li * 192,
              encg + (size_t)li * 192, encb + (size_t)li * 192,
              blkg + (size_t)blkid * 192, blkb + (size_t)blkid * 192,
              x1, nullptr, posn, xb, xpb);
      } else {
        ln_chain_k<false, false><<<NVOX / 4, 256, 0, stream>>>(x1, ffbuf, cur, xres,
            ln2g + (size_t)li * 192, ln2b + (size_t)li * 192,
            encg + (size_t)li * 192, encb + (size_t)li * 192,
            nullptr, nullptr, x1, nullptr, posn, xb, xpb);
      }
      cur = x1;
    }
    int newr = ib, na = r, nb = ia;
    r = newr; ia = na; ib = nb;
  }
}